// Round 5
// baseline (164.880 us; speedup 1.0000x reference)
//
#include <hip/hip_runtime.h>

// SpiralConv conv block: per-channel complex first-order recurrence
//   h[n] = c*h[n-1] + x[n],  h[-1] = last_conv_init[d],  out = Re(h)*x
// with c_d = exp(-exp(lmlg_d)) * e^{i*theta_d}.
//
// R5: three fully-parallel dispatches (R4's sc_out was latency-bound:
// 11.6% occupancy, 2.15 TB/s, per-block serial prefix re-scan).
//  k_sum:   chunk summaries; 4 step-groups x 8 steps combined via LDS.
//  k_carry: carry per (chunk,col) as an independent scan over summary
//           rows (L2-hot 4 MiB) — one thread per output, 32 waves/CU.
//  k_out:   group-split replay: local 8-step partial, LDS combine onto
//           carry, 8-step replay. Serial depth 16 instead of 32.

#define L_  4096
#define B_  4
#define D_  1024
#define BD_ (B_ * D_)      // 4096
#define NC  128            // chunks
#define CH  32             // steps per chunk
#define NG  4              // step-groups per chunk
#define GS  8              // steps per group
#define SLICES 4           // channel slices (D/256)
#define LDSP 9             // padded floats per (group,quad) slot

// helper: per-4-channel decay*rotation from lmlg/theta quads
__device__ __forceinline__ void make_c(const float4& lg, const float4& th,
                                       float* cr, float* ci) {
  float g0 = expf(-expf(lg.x)), g1 = expf(-expf(lg.y));
  float g2 = expf(-expf(lg.z)), g3 = expf(-expf(lg.w));
  cr[0] = g0 * cosf(th.x); ci[0] = g0 * sinf(th.x);
  cr[1] = g1 * cosf(th.y); ci[1] = g1 * sinf(th.y);
  cr[2] = g2 * cosf(th.z); ci[2] = g2 * sinf(th.z);
  cr[3] = g3 * cosf(th.w); ci[3] = g3 * sinf(th.w);
}
// c^GS (closed form)
__device__ __forceinline__ void make_c8(const float4& lg, const float4& th,
                                        float* Cr, float* Ci) {
  const float gs = (float)GS;
  float e0 = expf(lg.x), e1 = expf(lg.y), e2 = expf(lg.z), e3 = expf(lg.w);
  float g0 = expf(-e0 * gs), g1 = expf(-e1 * gs);
  float g2 = expf(-e2 * gs), g3 = expf(-e3 * gs);
  Cr[0] = g0 * cosf(th.x * gs); Ci[0] = g0 * sinf(th.x * gs);
  Cr[1] = g1 * cosf(th.y * gs); Ci[1] = g1 * sinf(th.y * gs);
  Cr[2] = g2 * cosf(th.z * gs); Ci[2] = g2 * sinf(th.z * gs);
  Cr[3] = g3 * cosf(th.w * gs); Ci[3] = g3 * sinf(th.w * gs);
}

// ---------------------------------------------------------------- k_sum ----
// Block: 256 thr = NG groups x 64 quads; covers (chunk k, batch b, 256-ch
// slice). Each group: 8-step local recurrence from 0; LDS combine
// s = ((p0*C8 + p1)*C8 + p2)*C8 + p3; g==0 threads write the summary.
__global__ __launch_bounds__(256) void k_sum(
    const float* __restrict__ x,
    const float* __restrict__ lmlg,
    const float* __restrict__ theta,
    float2* __restrict__ ws_sum) {
  const int t  = threadIdx.x;
  const int g  = t >> 6;
  const int q  = t & 63;
  const int bid = blockIdx.x;
  const int k   = bid / (B_ * SLICES);
  const int rem = bid % (B_ * SLICES);
  const int b   = rem / SLICES;
  const int sl  = rem % SLICES;
  const int d0  = sl * 256 + q * 4;

  float4 lg = *(const float4*)(lmlg + d0);
  float4 th = *(const float4*)(theta + d0);
  float cr[4], ci[4];
  make_c(lg, th, cr, ci);

  const size_t base = (size_t)(k * CH + g * GS) * BD_ + (size_t)b * D_ + d0;
  float4 xv[GS];
#pragma unroll
  for (int j = 0; j < GS; ++j)
    xv[j] = *(const float4*)(x + base + (size_t)j * BD_);

  float sr[4] = {0.f,0.f,0.f,0.f}, si[4] = {0.f,0.f,0.f,0.f};
#pragma unroll
  for (int j = 0; j < GS; ++j) {
    const float* xa = &xv[j].x;
#pragma unroll
    for (int c = 0; c < 4; ++c) {
      float nr = fmaf(cr[c], sr[c], fmaf(-ci[c], si[c], xa[c]));
      float ni = fmaf(cr[c], si[c], ci[c] * sr[c]);
      sr[c] = nr; si[c] = ni;
    }
  }

  __shared__ float lds[NG * 64 * LDSP];
  {
    float* p = &lds[(g * 64 + q) * LDSP];
#pragma unroll
    for (int c = 0; c < 4; ++c) { p[2*c] = sr[c]; p[2*c+1] = si[c]; }
  }
  __syncthreads();

  if (g == 0) {
    float Cr[4], Ci[4];
    make_c8(lg, th, Cr, Ci);
    float ar[4], ai[4];
#pragma unroll
    for (int c = 0; c < 4; ++c) { ar[c] = sr[c]; ai[c] = si[c]; }
    for (int gg = 1; gg < NG; ++gg) {
      const float* p = &lds[(gg * 64 + q) * LDSP];
#pragma unroll
      for (int c = 0; c < 4; ++c) {
        float pr = p[2*c], pi = p[2*c+1];
        float nr = fmaf(Cr[c], ar[c], fmaf(-Ci[c], ai[c], pr));
        float ni = fmaf(Cr[c], ai[c], fmaf(Ci[c], ar[c], pi));
        ar[c] = nr; ai[c] = ni;
      }
    }
    float2* sp = ws_sum + (size_t)k * BD_ + (size_t)b * D_ + d0;
#pragma unroll
    for (int c = 0; c < 4; ++c) sp[c] = make_float2(ar[c], ai[c]);
  }
}

// -------------------------------------------------------------- k_carry ----
// One thread per (chunk k, column col=b*D+d). Scan summary rows < k with
// jump factor C = c^CH: h = C*h + s. Rows are L2-hot (4 MiB buffer).
__global__ __launch_bounds__(256) void k_carry(
    const float* __restrict__ lmlg,
    const float* __restrict__ theta,
    const float* __restrict__ init,
    const float2* __restrict__ ws_sum,
    float2* __restrict__ ws_carry) {
  const int idx = blockIdx.x * 256 + threadIdx.x;   // k*BD + col
  const int k   = idx >> 12;                        // / BD_
  const int col = idx & (BD_ - 1);
  const int d   = col & (D_ - 1);
  float e  = expf(lmlg[d]);
  float th = theta[d];
  float gC = expf(-e * (float)CH);
  float aC = th * (float)CH;
  float Cr = gC * cosf(aC), Ci = gC * sinf(aC);
  float hr = init[d], hi = 0.f;
  const float2* sp = ws_sum + col;
  for (int kk = 0; kk < k; ++kk) {
    float2 s = sp[(size_t)kk * BD_];
    float nr = fmaf(Cr, hr, fmaf(-Ci, hi, s.x));
    float ni = fmaf(Cr, hi, fmaf(Ci, hr, s.y));
    hr = nr; hi = ni;
  }
  ws_carry[(size_t)k * BD_ + col] = make_float2(hr, hi);
}

// ---------------------------------------------------------------- k_out ----
// Same geometry as k_sum. Group g folds earlier groups' partials onto the
// global carry (<=3 complex fmas via LDS), then replays its 8 steps and
// writes out = Re(h)*x.
__global__ __launch_bounds__(256) void k_out(
    const float* __restrict__ x,
    const float* __restrict__ lmlg,
    const float* __restrict__ theta,
    const float2* __restrict__ ws_carry,
    float* __restrict__ out) {
  const int t  = threadIdx.x;
  const int g  = t >> 6;
  const int q  = t & 63;
  const int bid = blockIdx.x;
  const int k   = bid / (B_ * SLICES);
  const int rem = bid % (B_ * SLICES);
  const int b   = rem / SLICES;
  const int sl  = rem % SLICES;
  const int d0  = sl * 256 + q * 4;

  float4 lg = *(const float4*)(lmlg + d0);
  float4 th = *(const float4*)(theta + d0);
  float cr[4], ci[4];
  make_c(lg, th, cr, ci);

  const size_t base = (size_t)(k * CH + g * GS) * BD_ + (size_t)b * D_ + d0;
  float4 xv[GS];
#pragma unroll
  for (int j = 0; j < GS; ++j)
    xv[j] = *(const float4*)(x + base + (size_t)j * BD_);

  // local partial from zero state (consumed by later groups)
  float sr[4] = {0.f,0.f,0.f,0.f}, si[4] = {0.f,0.f,0.f,0.f};
#pragma unroll
  for (int j = 0; j < GS; ++j) {
    const float* xa = &xv[j].x;
#pragma unroll
    for (int c = 0; c < 4; ++c) {
      float nr = fmaf(cr[c], sr[c], fmaf(-ci[c], si[c], xa[c]));
      float ni = fmaf(cr[c], si[c], ci[c] * sr[c]);
      sr[c] = nr; si[c] = ni;
    }
  }

  __shared__ float lds[NG * 64 * LDSP];
  {
    float* p = &lds[(g * 64 + q) * LDSP];
#pragma unroll
    for (int c = 0; c < 4; ++c) { p[2*c] = sr[c]; p[2*c+1] = si[c]; }
  }

  // carry into chunk k for my 4 channels
  float hr[4], hi[4];
  {
    const float2* cp = ws_carry + (size_t)k * BD_ + (size_t)b * D_ + d0;
#pragma unroll
    for (int c = 0; c < 4; ++c) { float2 h = cp[c]; hr[c] = h.x; hi[c] = h.y; }
  }
  __syncthreads();

  // fold earlier groups: h = C8*h + p_i  for i = 0..g-1 (wave-uniform trip)
  if (g > 0) {
    float Cr[4], Ci[4];
    make_c8(lg, th, Cr, Ci);
    for (int i = 0; i < g; ++i) {
      const float* p = &lds[(i * 64 + q) * LDSP];
#pragma unroll
      for (int c = 0; c < 4; ++c) {
        float pr = p[2*c], pi = p[2*c+1];
        float nr = fmaf(Cr[c], hr[c], fmaf(-Ci[c], hi[c], pr));
        float ni = fmaf(Cr[c], hi[c], fmaf(Ci[c], hr[c], pi));
        hr[c] = nr; hi[c] = ni;
      }
    }
  }

  // replay my 8 steps, emit out = Re(h)*x
#pragma unroll
  for (int j = 0; j < GS; ++j) {
    const float* xa = &xv[j].x;
    float4 res; float* ra = &res.x;
#pragma unroll
    for (int c = 0; c < 4; ++c) {
      float nr = fmaf(cr[c], hr[c], fmaf(-ci[c], hi[c], xa[c]));
      float ni = fmaf(cr[c], hi[c], ci[c] * hr[c]);
      hr[c] = nr; hi[c] = ni;
      ra[c] = nr * xa[c];
    }
    *(float4*)(out + base + (size_t)j * BD_) = res;
  }
}

// ------------------------------------------------------------- fallback ----
__global__ __launch_bounds__(256) void sc_full(
    const float* __restrict__ x, const float* __restrict__ lmlg,
    const float* __restrict__ theta, const float* __restrict__ init,
    float* __restrict__ out) {
  const int idx = blockIdx.x * 256 + threadIdx.x;
  const int d   = idx & (D_ - 1);
  float g = expf(-expf(lmlg[d]));
  float cr = g * cosf(theta[d]), ci = g * sinf(theta[d]);
  float hr = init[d], hi = 0.f;
  const float* xp = x + idx;
  float*       op = out + idx;
  for (int n = 0; n < L_; ++n) {
    float xv = xp[(size_t)n * BD_];
    float nr = fmaf(cr, hr, fmaf(-ci, hi, xv));
    float ni = fmaf(cr, hi, ci * hr);
    hr = nr; hi = ni;
    op[(size_t)n * BD_] = nr * xv;
  }
}

// ---------------------------------------------------------------------------
extern "C" void kernel_launch(void* const* d_in, const int* in_sizes, int n_in,
                              void* d_out, int out_size, void* d_ws, size_t ws_size,
                              hipStream_t stream) {
  const float* x     = (const float*)d_in[0];
  const float* lmlg  = (const float*)d_in[1];
  const float* theta = (const float*)d_in[2];
  const float* init  = (const float*)d_in[3];
  float*  out = (float*)d_out;

  const size_t need = (size_t)2 * NC * BD_ * sizeof(float2);   // 8 MiB
  if (ws_size >= need) {
    float2* ws_sum   = (float2*)d_ws;
    float2* ws_carry = ws_sum + (size_t)NC * BD_;
    k_sum  <<<NC * B_ * SLICES, 256, 0, stream>>>(x, lmlg, theta, ws_sum);
    k_carry<<<NC * BD_ / 256,   256, 0, stream>>>(lmlg, theta, init, ws_sum, ws_carry);
    k_out  <<<NC * B_ * SLICES, 256, 0, stream>>>(x, lmlg, theta, ws_carry, out);
  } else {
    sc_full<<<BD_ / 256, 256, 0, stream>>>(x, lmlg, theta, init, out);
  }
}